// Round 11
// baseline (979.775 us; speedup 1.0000x reference)
//
#include <hip/hip_runtime.h>
#include <hip/hip_bf16.h>
#include <stdint.h>
#include <math.h>

#define S_LEN 2048
#define HIDDEN 2048
#define NHEAD 16
#define QLORA 768
#define KVLORA 512
#define QKNOPE 128
#define QKROPE 64
#define QKHEAD 192
#define VDIM 128
#define HIN 8
#define DIN 128
#define TOPKN 512
#define EPSF 1e-5f
#define DLAT 576
#define SCALE_ATT 0.07216878364870322f  // 192^-0.5

typedef __bf16 bf16x8 __attribute__((ext_vector_type(8)));
typedef float  f32x4  __attribute__((ext_vector_type(4)));

static __device__ __forceinline__ float wave_reduce_sum(float v) {
    #pragma unroll
    for (int off = 32; off > 0; off >>= 1) v += __shfl_down(v, off);
    return v;
}

static __device__ __forceinline__ void splitw(__bf16* __restrict__ H,
                                              __bf16* __restrict__ L,
                                              size_t idx, float v) {
    __bf16 h = (__bf16)v;
    H[idx] = h;
    L[idx] = (__bf16)(v - (float)h);
}

// async global->LDS, 16B per lane; lds base must be wave-uniform (HW: base + lane*16)
static __device__ __forceinline__ void gll16(const __bf16* g, __bf16* lds_base) {
    __builtin_amdgcn_global_load_lds(
        (const __attribute__((address_space(1))) uint32_t*)g,
        (__attribute__((address_space(3))) uint32_t*)lds_base, 16, 0, 0);
}

// =============== fused prep: all casts / splits / transpose in ONE launch ===============
#define PREP_BLOCKS 17280
__global__ __launch_bounds__(256) void prep_all(
        const float* __restrict__ hid,     __bf16* hidH,  __bf16* hidL,
        const float* __restrict__ wq_a,    __bf16* wqaH,  __bf16* wqaL,
        const float* __restrict__ idx_wq_b,__bf16* iwqH,  __bf16* iwqL,
        const float* __restrict__ idx_wk,  __bf16* iwkH,  __bf16* iwkL,
        const float* __restrict__ wq_b,    __bf16* wq_b_bf,
        const float* __restrict__ wkv_a,   __bf16* wkv_a_bf,
        const float* __restrict__ wkv_b,   __bf16* wkv_b_bf,
        const float* __restrict__ wo,      __bf16* wo_bf,
        __bf16* wknt) {
    int b = blockIdx.x, tid = threadIdx.x;
    const float* src; __bf16 *dH = nullptr, *dL = nullptr, *dC = nullptr;
    int base;
    if (b < 4096)        { src = hid;      dH = hidH; dL = hidL; base = b; }
    else if (b < 5632)   { src = wq_a;     dH = wqaH; dL = wqaL; base = b - 4096; }
    else if (b < 6400)   { src = idx_wq_b; dH = iwqH; dL = iwqL; base = b - 5632; }
    else if (b < 6656)   { src = idx_wk;   dH = iwkH; dL = iwkL; base = b - 6400; }
    else if (b < 8960)   { src = wq_b;     dC = wq_b_bf;  base = b - 6656; }
    else if (b < 10112)  { src = wkv_a;    dC = wkv_a_bf; base = b - 8960; }
    else if (b < 12160)  { src = wkv_b;    dC = wkv_b_bf; base = b - 10112; }
    else if (b < 16256)  { src = wo;       dC = wo_bf;    base = b - 12160; }
    else {
        int e = ((b - 16256) * 256 + tid) * 4;
        int c = e & 511, d = (e >> 9) & 127, h = e >> 16;
        f32x4 v = *(const f32x4*)(wkv_b + ((size_t)(h * 256 + d)) * 512 + c);
        #pragma unroll
        for (int j = 0; j < 4; ++j)
            wknt[(size_t)h * 65536 + (c + j) * 128 + d] = (__bf16)v[j];
        return;
    }
    int i = (base * 256 + tid) * 4;
    f32x4 v = *(const f32x4*)(src + i);
    if (dC) {
        #pragma unroll
        for (int j = 0; j < 4; ++j) dC[i + j] = (__bf16)v[j];
    } else {
        #pragma unroll
        for (int j = 0; j < 4; ++j) splitw(dH, dL, i + j, v[j]);
    }
}

// ---------------- bf16 MFMA GEMM core: C = A*B^T (global_load_lds staging) ----------------
#define GBM 128
#define GBN 64
#define GBK 32
template <typename OutT>
static __device__ __forceinline__ void gemm_s_core(
        const __bf16* __restrict__ A, const __bf16* __restrict__ B,
        OutT* __restrict__ C, int K, int lda, int ldb, int ldc,
        int bx, int by) {
    __shared__ __bf16 sAs[GBM * GBK];
    __shared__ __bf16 sBs[GBN * GBK];
    int tid = threadIdx.x;
    int lane = tid & 63, wid = tid >> 6;
    int quad = lane >> 4, l16 = lane & 15;
    int wm = wid >> 1, wn = wid & 1;
    int row0 = by * GBM, col0 = bx * GBN;
    int lr = lane >> 2, lk = (lane & 3) * 8;   // lane -> (row-in-chunk, k-offset)

    f32x4 acc[4][2] = {};

    for (int k0 = 0; k0 < K; k0 += GBK) {
        #pragma unroll
        for (int c = 0; c < 2; ++c) {
            int rb = (wid * 2 + c) * 16;
            gll16(A + (size_t)(row0 + rb + lr) * lda + k0 + lk, sAs + rb * GBK);
        }
        gll16(B + (size_t)(col0 + wid * 16 + lr) * ldb + k0 + lk, sBs + wid * 16 * GBK);
        __syncthreads();
        bf16x8 af[4], bfr[2];
        #pragma unroll
        for (int mi = 0; mi < 4; ++mi)
            af[mi] = *(const bf16x8*)&sAs[(wm * 64 + mi * 16 + l16) * GBK + quad * 8];
        #pragma unroll
        for (int ni = 0; ni < 2; ++ni)
            bfr[ni] = *(const bf16x8*)&sBs[(wn * 32 + ni * 16 + l16) * GBK + quad * 8];
        #pragma unroll
        for (int mi = 0; mi < 4; ++mi)
            #pragma unroll
            for (int ni = 0; ni < 2; ++ni)
                acc[mi][ni] = __builtin_amdgcn_mfma_f32_16x16x32_bf16(
                    af[mi], bfr[ni], acc[mi][ni], 0, 0, 0);
        __syncthreads();
    }
    #pragma unroll
    for (int mi = 0; mi < 4; ++mi)
        #pragma unroll
        for (int ni = 0; ni < 2; ++ni)
            #pragma unroll
            for (int r = 0; r < 4; ++r) {
                int row = row0 + wm * 64 + mi * 16 + quad * 4 + r;
                int col = col0 + wn * 32 + ni * 16 + l16;
                C[(size_t)row * ldc + col] = (OutT)acc[mi][ni][r];
            }
}

template <typename OutT>
__global__ __launch_bounds__(256) void gemm_s(const __bf16* __restrict__ A,
                                              const __bf16* __restrict__ B,
                                              OutT* __restrict__ C,
                                              int K, int lda, int ldb, int ldc,
                                              long sA, long sB, long sC) {
    gemm_s_core<OutT>(A + (size_t)blockIdx.z * sA, B + (size_t)blockIdx.z * sB,
                      C + (size_t)blockIdx.z * sC, K, lda, ldb, ldc,
                      blockIdx.x, blockIdx.y);
}

// ------------- split-bf16 (~f32) MFMA GEMM core: C = Ah*Bh + Ah*Bl + Al*Bh -------------
template <bool CAUSAL>
static __device__ __forceinline__ void gemm3_core(
        const __bf16* __restrict__ Ah, const __bf16* __restrict__ Al,
        const __bf16* __restrict__ Bh, const __bf16* __restrict__ Bl,
        float* __restrict__ C, int K, int lda, int ldb, int ldc,
        int row_base, int bx, int by) {
    int row0 = by * GBM + row_base, col0 = bx * GBN;
    if (CAUSAL && col0 > row0 + GBM - 1) return;
    __shared__ __bf16 sAh[GBM * GBK], sAl[GBM * GBK];
    __shared__ __bf16 sBh[GBN * GBK], sBl[GBN * GBK];
    int tid = threadIdx.x;
    int lane = tid & 63, wid = tid >> 6;
    int quad = lane >> 4, l16 = lane & 15;
    int wm = wid >> 1, wn = wid & 1;
    int lr = lane >> 2, lk = (lane & 3) * 8;

    f32x4 acc[4][2] = {};

    for (int k0 = 0; k0 < K; k0 += GBK) {
        #pragma unroll
        for (int c = 0; c < 2; ++c) {
            int rb = (wid * 2 + c) * 16;
            size_t go = (size_t)(row0 + rb + lr) * lda + k0 + lk;
            gll16(Ah + go, sAh + rb * GBK);
            gll16(Al + go, sAl + rb * GBK);
        }
        {
            size_t go = (size_t)(col0 + wid * 16 + lr) * ldb + k0 + lk;
            gll16(Bh + go, sBh + wid * 16 * GBK);
            gll16(Bl + go, sBl + wid * 16 * GBK);
        }
        __syncthreads();
        bf16x8 afh[4], afl[4], bfh[2], bfl[2];
        #pragma unroll
        for (int mi = 0; mi < 4; ++mi) {
            int o = (wm * 64 + mi * 16 + l16) * GBK + quad * 8;
            afh[mi] = *(const bf16x8*)&sAh[o];
            afl[mi] = *(const bf16x8*)&sAl[o];
        }
        #pragma unroll
        for (int ni = 0; ni < 2; ++ni) {
            int o = (wn * 32 + ni * 16 + l16) * GBK + quad * 8;
            bfh[ni] = *(const bf16x8*)&sBh[o];
            bfl[ni] = *(const bf16x8*)&sBl[o];
        }
        #pragma unroll
        for (int mi = 0; mi < 4; ++mi)
            #pragma unroll
            for (int ni = 0; ni < 2; ++ni) {
                acc[mi][ni] = __builtin_amdgcn_mfma_f32_16x16x32_bf16(
                    afl[mi], bfh[ni], acc[mi][ni], 0, 0, 0);
                acc[mi][ni] = __builtin_amdgcn_mfma_f32_16x16x32_bf16(
                    afh[mi], bfl[ni], acc[mi][ni], 0, 0, 0);
                acc[mi][ni] = __builtin_amdgcn_mfma_f32_16x16x32_bf16(
                    afh[mi], bfh[ni], acc[mi][ni], 0, 0, 0);
            }
        __syncthreads();
    }
    #pragma unroll
    for (int mi = 0; mi < 4; ++mi)
        #pragma unroll
        for (int ni = 0; ni < 2; ++ni)
            #pragma unroll
            for (int r = 0; r < 4; ++r) {
                int row = row0 + wm * 64 + mi * 16 + quad * 4 + r;
                int col = col0 + wn * 32 + ni * 16 + l16;
                C[(size_t)row * ldc + col] = acc[mi][ni][r];
            }
}

// q_lora GEMM with K-split x4 (underfilled otherwise: 192 blocks on 256 CUs)
__global__ __launch_bounds__(256) void gemm3_ks(const __bf16* __restrict__ Ah,
                                                const __bf16* __restrict__ Al,
                                                const __bf16* __restrict__ Bh,
                                                const __bf16* __restrict__ Bl,
                                                float* __restrict__ Cpart,
                                                int Ksub, int lda, int ldb, int ldc,
                                                long sC) {
    int bz = blockIdx.z, koff = bz * Ksub;
    gemm3_core<false>(Ah + koff, Al + koff, Bh + koff, Bl + koff,
                      Cpart + (size_t)bz * sC, Ksub, lda, ldb, ldc, 0,
                      blockIdx.x, blockIdx.y);
}

// ============ fused mid GEMMs: qbuf | kv | iqraw | ikraw (independent) ============
__global__ __launch_bounds__(256) void fused_mid(
        const __bf16* __restrict__ qlH, const __bf16* __restrict__ qlL,
        const __bf16* __restrict__ wq_b_bf, __bf16* __restrict__ qbuf_bf,
        const __bf16* __restrict__ hidH, const __bf16* __restrict__ hidL,
        const __bf16* __restrict__ wkv_a_bf, float* __restrict__ kv,
        const __bf16* __restrict__ iwqH, const __bf16* __restrict__ iwqL,
        float* __restrict__ iqraw,
        const __bf16* __restrict__ iwkH, const __bf16* __restrict__ iwkL,
        float* __restrict__ ikraw) {
    int b = blockIdx.x;
    if (b < 768) {            // qbuf: [2048 x 3072] = ql * wq_b^T, K=768
        gemm_s_core<__bf16>(qlH, wq_b_bf, qbuf_bf, QLORA, QLORA, QLORA,
                            NHEAD * QKHEAD, b % 48, b / 48);
    } else if (b < 912) {     // kv: [2048 x 576] = hid * wkv_a^T, K=2048
        int r = b - 768;
        gemm_s_core<float>(hidH, wkv_a_bf, kv, HIDDEN, HIDDEN, HIDDEN, DLAT,
                           r % 9, r / 9);
    } else if (b < 1168) {    // iqraw: [2048 x 1024] = ql * idx_wq_b^T, K=768 (~f32)
        int r = b - 912;
        gemm3_core<false>(qlH, qlL, iwqH, iwqL, iqraw, QLORA, QLORA, QLORA,
                          HIN * DIN, 0, r & 15, r >> 4);
    } else {                  // ikraw: [2048 x 128] = hid * idx_wk^T, K=2048 (~f32)
        int r = b - 1168;
        gemm3_core<false>(hidH, hidL, iwkH, iwkL, ikraw, HIDDEN, HIDDEN, HIDDEN,
                          DIN, 0, r & 1, r >> 1);
    }
}

// ============ fused stage-2 GEMMs: qeff-nope (batched) | iscore (causal) ============
// iscore region: r in [0,384) ONLY (32 cols x 12 row-blocks, rows 512..2047).
__global__ __launch_bounds__(256) void fused2(
        const __bf16* __restrict__ qbuf_bf, const __bf16* __restrict__ wknt,
        __bf16* __restrict__ qeff,
        const __bf16* __restrict__ cqH, const __bf16* __restrict__ cqL,
        const __bf16* __restrict__ ikH, const __bf16* __restrict__ ikL,
        float* __restrict__ iscore) {
    int b = blockIdx.x;
    if (b < 2048) {           // qeff[...,0:512] per head: q_nope * wknt^T, K=128
        int bx = b & 7, by = (b >> 3) & 15, bz = b >> 7;
        gemm_s_core<__bf16>(qbuf_bf + bz * QKHEAD, wknt + (size_t)bz * 512 * 128,
                            qeff + bz * DLAT, 128, NHEAD * QKHEAD, 128,
                            NHEAD * DLAT, bx, by);
    } else {                  // iscore rows 512..2047, lower-triangle blocks, K=128
        int r = b - 2048;     // r in [0, 384)
        gemm3_core<true>(cqH, cqL, ikH, ikL, iscore, DIN, DIN, DIN, S_LEN,
                         TOPKN, r & 31, r >> 5);
    }
}

// ---------------- RMSNorm of 4 K-split partial sums -> split hi/lo bf16 ----------------
__global__ __launch_bounds__(256) void rmsnorm_split4(const float* __restrict__ p,
                                                      long ps,
                                                      const float* __restrict__ w,
                                                      __bf16* __restrict__ yH,
                                                      __bf16* __restrict__ yL, int ncols) {
    int row = blockIdx.x, tid = threadIdx.x;
    const float* p0 = p + (size_t)row * ncols;
    float ss = 0.f;
    for (int c = tid; c < ncols; c += 256) {
        float v = p0[c] + p0[ps + c] + p0[2 * ps + c] + p0[3 * ps + c];
        ss += v * v;
    }
    __shared__ float red[4];
    ss = wave_reduce_sum(ss);
    if ((tid & 63) == 0) red[tid >> 6] = ss;
    __syncthreads();
    float tot = red[0] + red[1] + red[2] + red[3];
    float inv = rsqrtf(tot / (float)ncols + EPSF);
    for (int c = tid; c < ncols; c += 256) {
        float v = p0[c] + p0[ps + c] + p0[2 * ps + c] + p0[3 * ps + c];
        splitw(yH, yL, (size_t)row * ncols + c, v * inv * w[c]);
    }
}

// ===== fused post: rope_qeff | kv_post | ik_post | cq2 — one block per position s =====
__global__ __launch_bounds__(256) void fused_post(
        const __bf16* __restrict__ qbuf, __bf16* __restrict__ qeff,
        const float* __restrict__ kv, const float* __restrict__ kvw,
        __bf16* __restrict__ klat,
        const float* __restrict__ ikraw, const float* __restrict__ lnw,
        const float* __restrict__ lnb, __bf16* __restrict__ ikH, __bf16* __restrict__ ikL,
        const float* __restrict__ iqraw, const float* __restrict__ hid,
        const float* __restrict__ iww, __bf16* __restrict__ cqH, __bf16* __restrict__ cqL,
        const float* __restrict__ cosT, const float* __restrict__ sinT) {
    int s = blockIdx.x, tid = threadIdx.x;
    int lane = tid & 63, wid = tid >> 6;

    // ---- A: rope on q -> qeff[...,512:576] ----
    for (int i = tid; i < NHEAD * 32; i += 256) {
        int h = i >> 5, d = i & 31;
        const __bf16* base = qbuf + (size_t)s * (NHEAD * QKHEAD) + h * QKHEAD + QKNOPE;
        float x1 = (float)base[d], x2 = (float)base[d + 32];
        float c1 = cosT[s * 64 + d],      s1 = sinT[s * 64 + d];
        float c2 = cosT[s * 64 + d + 32], s2 = sinT[s * 64 + d + 32];
        __bf16* o = qeff + (size_t)s * (NHEAD * DLAT) + h * DLAT + 512;
        o[d]      = (__bf16)(x1 * c1 - x2 * s1);
        o[d + 32] = (__bf16)(x2 * c2 + x1 * s2);
    }

    // ---- B: kv rmsnorm 512 + rope 64 -> klat ----
    {
        const float* row = kv + (size_t)s * DLAT;
        float ss = 0.f;
        for (int c = tid; c < KVLORA; c += 256) { float v = row[c]; ss += v * v; }
        __shared__ float redB[4];
        ss = wave_reduce_sum(ss);
        if (lane == 0) redB[wid] = ss;
        __syncthreads();
        float tot = redB[0] + redB[1] + redB[2] + redB[3];
        float inv = rsqrtf(tot / (float)KVLORA + EPSF);
        __bf16* orow = klat + (size_t)s * DLAT;
        for (int c = tid; c < KVLORA; c += 256)
            orow[c] = (__bf16)(row[c] * inv * kvw[c]);
        if (tid < 32) {
            int d = tid;
            float x1 = row[KVLORA + d], x2 = row[KVLORA + d + 32];
            float c1 = cosT[s * 64 + d],      s1 = sinT[s * 64 + d];
            float c2 = cosT[s * 64 + d + 32], s2 = sinT[s * 64 + d + 32];
            orow[512 + d]      = (__bf16)(x1 * c1 - x2 * s1);
            orow[512 + d + 32] = (__bf16)(x2 * c2 + x1 * s2);
        }
    }

    // ---- C: ik layer_norm(128) + rope -> split ----
    {
        float x = (tid < DIN) ? ikraw[(size_t)s * DIN + tid] : 0.f;
        __shared__ float redC1[4], redC2[4], sy[DIN];
        float sm = wave_reduce_sum(x);
        if (lane == 0) redC1[wid] = sm;
        __syncthreads();
        float mean = (redC1[0] + redC1[1] + redC1[2] + redC1[3]) / (float)DIN;
        float dx = (tid < DIN) ? (x - mean) : 0.f;
        float vs = wave_reduce_sum(dx * dx);
        if (lane == 0) redC2[wid] = vs;
        __syncthreads();
        float var = (redC2[0] + redC2[1] + redC2[2] + redC2[3]) / (float)DIN;
        if (tid < DIN) sy[tid] = dx * rsqrtf(var + EPSF) * lnw[tid] + lnb[tid];
        __syncthreads();
        size_t ro = (size_t)s * DIN;
        if (tid < 32) {
            int d = tid;
            float c1 = cosT[s * 64 + d],      s1 = sinT[s * 64 + d];
            float c2 = cosT[s * 64 + d + 32], s2 = sinT[s * 64 + d + 32];
            splitw(ikH, ikL, ro + d,      sy[d] * c1 - sy[d + 32] * s1);
            splitw(ikH, ikL, ro + d + 32, sy[d + 32] * c2 + sy[d] * s2);
        } else if (tid >= 64 && tid < DIN) {
            splitw(ikH, ikL, ro + tid, sy[tid]);
        }
        __syncthreads();
    }

    // ---- D: iw dots + fold into roped iq -> cq split ----
    {
        __shared__ float redD[4][HIN], siw[HIN];
        float a8[HIN] = {};
        const float* xr = hid + (size_t)s * HIDDEN;
        for (int c = tid; c < HIDDEN; c += 256) {
            float x = xr[c];
            #pragma unroll
            for (int h = 0; h < HIN; ++h) a8[h] += x * iww[h * HIDDEN + c];
        }
        #pragma unroll
        for (int h = 0; h < HIN; ++h) a8[h] = wave_reduce_sum(a8[h]);
        if (lane == 0)
            #pragma unroll
            for (int h = 0; h < HIN; ++h) redD[wid][h] = a8[h];
        __syncthreads();
        if (tid < HIN)
            siw[tid] = redD[0][tid] + redD[1][tid] + redD[2][tid] + redD[3][tid];
        __syncthreads();
        if (tid < DIN) {
            int d = tid;
            float acc = 0.f;
            float c1 = 0.f, s1 = 0.f;
            if (d < 64) { c1 = cosT[s * 64 + d]; s1 = sinT[s * 64 + d]; }
            #pragma unroll
            for (int h = 0; h < HIN; ++h) {
                const float* base = iqraw + ((size_t)s * HIN + h) * DIN;
                float v;
                if (d < 32)       v = base[d] * c1 - base[d + 32] * s1;
                else if (d < 64)  v = base[d] * c1 + base[d - 32] * s1;
                else              v = base[d];
                acc += siw[h] * v;
            }
            splitw(cqH, cqL, (size_t)s * DIN + d, acc * 0.03125f);
        }
    }
}

// ================= shared-memory structs for the merged topk/attention =================
#define SKS 584   // shorts per sK row (1168 B)
struct AttnSmem {
    short sK[32 * SKS];            // 37376 B
    float s_part[2][16][37];       // 4736
    float s_S[16][38];             // 2432
    float s_m[16], s_l[16], s_alpha[16], s_inv[16];   // 256  -> 44800 total
};
struct TopkSmem {
    uint32_t skey[S_LEN];          // 8192
    int hist[256];                 // 1024
    int wtot[4];
    uint32_t sp;
    int sr;
    int pos;
};

// inclusive suffix sum over 256 threads (1 barrier, shfl-based)
static __device__ __forceinline__ int suffix_scan256(int v, int tid, int* wtot) {
    int lane = tid & 63, w = tid >> 6;
    #pragma unroll
    for (int off = 1; off < 64; off <<= 1) {
        int u = __shfl_down(v, off);
        v += (lane + off < 64) ? u : 0;
    }
    int wt = __shfl(v, 0);
    if (lane == 0) wtot[w] = wt;
    __syncthreads();
    int add = 0;
    #pragma unroll
    for (int w2 = 0; w2 < 4; ++w2) add += (w2 > w) ? wtot[w2] : 0;
    return v + add;
}

// exclusive prefix sum over 256 threads (1 barrier, shfl-based)
static __device__ __forceinline__ int prefix_scan256_excl(int v, int tid, int* wtot) {
    int lane = tid & 63, w = tid >> 6;
    int orig = v;
    #pragma unroll
    for (int off = 1; off < 64; off <<= 1) {
        int u = __shfl_up(v, off);
        v += (lane >= off) ? u : 0;
    }
    int wt = __shfl(v, 63);
    if (lane == 0) wtot[w] = wt;
    __syncthreads();
    int add = 0;
    #pragma unroll
    for (int w2 = 0; w2 < 4; ++w2) add += (w2 < w) ? wtot[w2] : 0;
    return v + add - orig;
}

// ---- exact top-512 for one row q >= 512 (radix select, shfl scans) ----
static __device__ void topk_body(TopkSmem& sm, int qi,
                                 const float* __restrict__ iscore,
                                 int* __restrict__ topk) {
    int q = TOPKN + qi;
    int n = q + 1;
    int tid = threadIdx.x;
    const float* row = iscore + (size_t)q * S_LEN;
    for (int i = tid; i < n; i += 256) {
        uint32_t u = __float_as_uint(row[i]);
        sm.skey[i] = (u & 0x80000000u) ? ~u : (u | 0x80000000u);
    }
    uint32_t prefix = 0;
    int remk = TOPKN;
    for (int pass = 0; pass < 4; ++pass) {
        int shift = 24 - 8 * pass;
        uint32_t pmask = pass ? (0xFFFFFFFFu << (shift + 8)) : 0u;
        sm.hist[tid] = 0;
        __syncthreads();                  // covers skey staging (pass 0) + hist zero
        for (int i = tid; i < n; i += 256) {
            uint32_t u = sm.skey[i];
            if ((u & pmask) == prefix) atomicAdd(&sm.hist[(u >> shift) & 255], 1);
        }
        __syncthreads();
        int cnt = sm.hist[tid];
        int Sb = suffix_scan256(cnt, tid, sm.wtot);
        int Snext = Sb - cnt;
        if (Sb >= remk && Snext < remk) {
            sm.sp = prefix | ((uint32_t)tid << shift);
            sm.sr = remk - Snext;
        }
        __syncthreads();
        prefix = sm.sp;
        remk = sm.sr;
    }
    if (tid == 0) sm.pos = 0;
    __syncthreads();
    int* orow = topk + (size_t)q * TOPKN;
    for (int i = tid; i < n; i += 256) {
        if (sm.skey[i] > prefix) { int p = atomicAdd(&sm.pos, 1); orow[p] = i; }
    }
    __syncthreads();
    int base = sm.pos;   // == TOPKN - remk
    int chunk = (n + 255) >> 8;
    int lo = tid * chunk, hiEnd = lo + chunk;
    if (hiEnd > n) hiEnd = n;
    int cnt = 0;
    for (int i = lo; i < hiEnd; ++i) cnt += (sm.skey[i] == prefix);
    int r = prefix_scan256_excl(cnt, tid, sm.wtot);
    for (int i = lo; i < hiEnd && r < remk; ++i) {
        if (sm.skey[i] == prefix) { orow[base + r] = i; ++r; }
    }
}

// ---- absorbed-MLA flash attention body for one q (R7 structure + gll16 staging) ----
static __device__ void attn_body(AttnSmem& sm, int q,
                                 const __bf16* __restrict__ qeff,
                                 const __bf16* __restrict__ klat,
                                 const int* __restrict__ topk,
                                 __bf16* __restrict__ o_lat) {
    int tid = threadIdx.x;
    int lane = tid & 63, wid = tid >> 6;
    int l16 = lane & 15, quad = lane >> 4;
    int wn = wid & 1, wk = wid >> 1;

    int L = (q < TOPKN) ? (q + 1) : TOPKN;
    int nt = (L + 31) >> 5;
    const int* idxr = topk + (size_t)q * TOPKN;   // only deref'd when q >= TOPKN

    bf16x8 qf[9];
    const __bf16* qrow = qeff + (size_t)q * (NHEAD * DLAT) + l16 * DLAT + wk * 288 + quad * 8;
    #pragma unroll
    for (int s = 0; s < 9; ++s) qf[s] = *(const bf16x8*)(qrow + s * 32);

    if (tid < 16) { sm.s_m[tid] = -1e30f; sm.s_l[tid] = 0.f; }

    f32x4 oacc[8];
    #pragma unroll
    for (int i = 0; i < 8; ++i) oacc[i] = (f32x4){0.f, 0.f, 0.f, 0.f};

    for (int t = 0; t < nt; ++t) {
        // ---- stage 32 gathered Klat rows: per wave 8 rows, each 1024B gll16 + 128B tail
        #pragma unroll
        for (int i = 0; i < 8; ++i) {
            int row = wid * 8 + i;
            int ki = t * 32 + row;
            int gk = 0;
            if (ki < L) gk = (q < TOPKN) ? ki : idxr[ki];
            const __bf16* src = klat + (size_t)gk * DLAT;
            gll16(src + lane * 8, (__bf16*)&sm.sK[row * SKS]);
            if (lane < 8)
                *(uint4*)&sm.sK[row * SKS + 512 + lane * 8] =
                    *(const uint4*)(src + 512 + lane * 8);
        }
        __syncthreads();

        f32x4 sacc = {0.f, 0.f, 0.f, 0.f};
        const short* kbase = sm.sK + (wn * 16 + l16) * SKS + wk * 288 + quad * 8;
        #pragma unroll
        for (int s = 0; s < 9; ++s) {
            bf16x8 kf = *(const bf16x8*)(kbase + s * 32);
            sacc = __builtin_amdgcn_mfma_f32_16x16x32_bf16(qf[s], kf, sacc, 0, 0, 0);
        }
        #pragma unroll
        for (int r = 0; r < 4; ++r)
            sm.s_part[wk][quad * 4 + r][wn * 16 + l16] = sacc[r];
        __syncthreads();

        {
            int h = tid >> 4, k0 = (tid & 15) * 2;
            float v0 = -1e30f, v1 = -1e30f;
            if (t * 32 + k0 < L)
                v0 = (sm.s_part[0][h][k0] + sm.s_part[1][h][k0]) * SCALE_ATT;
            if (t * 32 + k0 + 1 < L)
                v1 = (sm.s_part[0][h][k0 + 1] + sm.s_part[1][h][k0 + 1]) * SCALE_ATT;
            float mt = fmaxf(v0, v1);
            #pragma unroll
            for (int o = 1; o < 16; o <<= 1) mt = fmaxf(mt, __shfl_xor(mt, o));
            float mold = sm.s_m[h];
            float mnew = fmaxf(mold, mt);
            float p0 = __expf(v0 - mnew), p1 = __expf(v1 - mnew);
            float ls = p0 + p1;
            #pragma unroll
            for (int o = 1; o < 16; o <<= 1) ls += __shfl_xor(ls, o);
            *(float2*)&sm.s_S[h][k0] = make_float2(p0, p1);
            if ((tid & 15) == 0) {
                float alpha = __expf(mold - mnew);
                sm.s_alpha[h] = alpha;
                sm.s_m[h] = mnew;
                sm.s_l[h] = sm.s_l[h] * alpha + ls;
            }
        }
        __syncthreads();

        f32x4 al4 = *(const f32x4*)&sm.s_alpha[quad * 4];
        // P A-frag, k-slot permutation j -> j^quad, loaded as 4 aligned b64s
        bf16x8 pf;
        int qhi = quad & 2, qlo = quad & 1;
        #pragma unroll
        for (int p = 0; p < 4; ++p) {
            float2 v = *(const float2*)&sm.s_S[l16][quad * 8 + ((2 * p) ^ qhi)];
            float e0 = qlo ? v.y : v.x, e1 = qlo ? v.x : v.y;
            pf[2 * p]     = (__bf16)e0;
            pf[2 * p + 1] = (__bf16)e1;
        }
        const __bf16* sKb = (const __bf16*)sm.sK;
        #pragma unroll
        for (int n = 0; n < 8; ++n) {
            int dim = wid * 128 + n * 16 + l16;
            bf16x8 vf;
            #pragma unroll
            for (int j = 0; j < 8; ++j)
                vf[j] = sKb[(quad * 8 + (j ^ quad)) * SKS + dim];
            #pragma unroll
            for (int r = 0; r < 4; ++r) oacc[n][r] *= al4[r];
            oacc[n] = __builtin_amdgcn_mfma_f32_16x16x32_bf16(pf, vf, oacc[n], 0, 0, 0);
        }
        __syncthreads();
    }

    if (tid < 16) sm.s_inv[tid] = 1.f / sm.s_l[tid];
    __syncthreads();
    f32x4 inv4 = *(const f32x4*)&sm.s_inv[quad * 4];
    #pragma unroll
    for (int n = 0; n < 8; ++n) {
        int dim = wid * 128 + n * 16 + l16;
        #pragma unroll
        for (int r = 0; r < 4; ++r) {
            int h = quad * 4 + r;
            o_lat[(size_t)q * 8192 + h * 512 + dim] = (__bf16)(oacc[n][r] * inv4[r]);
        }
    }
}

// ===== merged launch: blocks 0..511 attention rows q<512 (no topk dep) | 512..2047 topk =====
__global__ __launch_bounds__(256) void topk_attnA(
        const float* __restrict__ iscore, int* __restrict__ topk,
        const __bf16* __restrict__ qeff, const __bf16* __restrict__ klat,
        __bf16* __restrict__ o_lat) {
    __shared__ __align__(16) char pool[sizeof(AttnSmem)];
    int b = blockIdx.x;
    if (b < 512) {
        attn_body(*(AttnSmem*)pool, (b * 997) & 511, qeff, klat, nullptr, o_lat);
    } else {
        topk_body(*(TopkSmem*)pool, b - 512, iscore, topk);
    }
}

// ===== attention rows q >= 512 (needs topk) =====
__global__ __launch_bounds__(256) void attn2b(const __bf16* __restrict__ qeff,
                                              const __bf16* __restrict__ klat,
                                              const int* __restrict__ topk,
                                              __bf16* __restrict__ o_lat) {
    __shared__ __align__(16) char pool[sizeof(AttnSmem)];
    int q = TOPKN + (blockIdx.x * 997) % (S_LEN - TOPKN);
    attn_body(*(AttnSmem*)pool, q, qeff, klat, topk, o_lat);
}

extern "C" void kernel_launch(void* const* d_in, const int* in_sizes, int n_in,
                              void* d_out, int out_size, void* d_ws, size_t ws_size,
                              hipStream_t stream) {
    const float* hid          = (const float*)d_in[0];
    const float* cosT         = (const float*)d_in[1];
    const float* sinT         = (const float*)d_in[2];
    const float* wq_a         = (const float*)d_in[3];
    const float* q_a_norm_w   = (const float*)d_in[4];
    const float* wq_b         = (const float*)d_in[5];
    const float* wkv_a        = (const float*)d_in[6];
    const float* kv_a_norm_w  = (const float*)d_in[7];
    const float* wkv_b        = (const float*)d_in[8];
    const float* wo           = (const float*)d_in[9];
    const float* idx_wq_b     = (const float*)d_in[10];
    const float* idx_wk       = (const float*)d_in[11];
    const float* idx_k_norm_w = (const float*)d_in[12];
    const float* idx_k_norm_b = (const float*)d_in[13];
    const float* idx_weights_w= (const float*)d_in[14];
    float* out = (float*)d_out;

    char* ws = (char*)d_ws;
    size_t off = 0;
    auto alloc = [&](size_t nbytes) {
        void* p = (void*)(ws + off);
        off += (nbytes + 255) & ~(size_t)255;
        return p;
    };
    __bf16* qbuf_bf  = (__bf16*)alloc((size_t)S_LEN * NHEAD * QKHEAD * 2);
    float*  kv       = (float*) alloc((size_t)S_LEN * DLAT * 4);
    __bf16* klat_bf  = (__bf16*)alloc((size_t)S_LEN * DLAT * 2);
    __bf16* qeff_bf  = (__bf16*)alloc((size_t)S_LEN * NHEAD * DLAT * 2);
    int*    topk     = (int*)   alloc((size_t)S_LEN * TOPKN * 4);
    // union B: [hidH | wkv_a_bf] (early) / attn_o_bf (late)
    char* uB = (char*)alloc((size_t)S_LEN * HIDDEN * 2 + (size_t)DLAT * HIDDEN * 2);
    __bf16* hidH      = (__bf16*)uB;
    __bf16* wkv_a_bf  = (__bf16*)(uB + (size_t)S_LEN * HIDDEN * 2);
    __bf16* attn_o_bf = (__bf16*)uB;
    __bf16* hidL      = (__bf16*)alloc((size_t)S_LEN * HIDDEN * 2);
    // union C: qpart (earliest, 25.2MB) / indexer block (early) / o_lat (late, 33.6MB)
    char* uC = (char*)alloc((size_t)S_LEN * NHEAD * 512 * 2);
    float*  qpart    = (float*)uC;               // 4 x [2048 x 768] K-split partials
    __bf16* o_lat_bf = (__bf16*)uC;
    float* iqraw  = (float*)uC;
    float* ikraw  = (float*)(uC + 8388608);
    float* iscore = (float*)(uC + 11599872);
    __bf16* wq_b_bf  = (__bf16*)alloc((size_t)(NHEAD * QKHEAD) * QLORA * 2);
    __bf16* wkv_b_bf = (__bf16*)alloc((size_t)(NHEAD * 256) * KVLORA * 2);
    __bf16* wknt_bf  = (__bf16*)alloc((size_t)NHEAD * 512 * 128 * 2);
    __bf16* wo_bf    = (__bf16*)alloc((size_t)HIDDEN * (NHEAD * VDIM) * 2);
    __bf16* wqaH = (__bf16*)alloc((size_t)QLORA * HIDDEN * 2);
    __bf16* wqaL = (__bf16*)alloc((size_t)QLORA * HIDDEN * 2);
    __bf16* qlH  = (__bf16*)alloc((size_t)S_LEN * QLORA * 2);
    __bf16* qlL  = (__bf16*)alloc((size_t)S_LEN * QLORA * 2);
    __bf16* iwqH = (__bf16*)alloc((size_t)(HIN * DIN) * QLORA * 2);
    __bf16* iwqL = (__bf16*)alloc((size_t)(HIN * DIN) * QLORA * 2);
    __bf16* iwkH = (__bf16*)alloc((size_t)DIN * HIDDEN * 2);
    __bf16* iwkL = (__bf16*)alloc((size_t)DIN * HIDDEN * 2);
    __bf16* ikH  = (__bf16*)alloc((size_t)S_LEN * DIN * 2);
    __bf16* ikL  = (__bf16*)alloc((size_t)S_LEN * DIN * 2);
    __bf16* cqH  = (__bf16*)alloc((size_t)S_LEN * DIN * 2);
    __bf16* cqL  = (__bf16*)alloc((size_t)S_LEN * DIN * 2);
    (void)ws_size; (void)in_sizes; (void)n_in; (void)out_size;

    dim3 blk(256);

    // 1. all casts / splits / transpose in one launch
    prep_all<<<PREP_BLOCKS, blk, 0, stream>>>(
        hid, hidH, hidL, wq_a, wqaH, wqaL, idx_wq_b, iwqH, iwqL,
        idx_wk, iwkH, iwkL, wq_b, wq_b_bf, wkv_a, wkv_a_bf,
        wkv_b, wkv_b_bf, wo, wo_bf, wknt_bf);

    // 2. q_lora (~f32, K-split x4 for occupancy) + rmsnorm(sum of partials)
    gemm3_ks<<<dim3(QLORA / GBN, S_LEN / GBM, 4), blk, 0, stream>>>(
        hidH, hidL, wqaH, wqaL, qpart, HIDDEN / 4, HIDDEN, HIDDEN, QLORA,
        (long)S_LEN * QLORA);
    rmsnorm_split4<<<S_LEN, 256, 0, stream>>>(qpart, (long)S_LEN * QLORA,
                                              q_a_norm_w, qlH, qlL, QLORA);

    // 3. four independent GEMMs in one launch: qbuf | kv | iqraw | ikraw
    fused_mid<<<1200, blk, 0, stream>>>(qlH, qlL, wq_b_bf, qbuf_bf,
                                        hidH, hidL, wkv_a_bf, kv,
                                        iwqH, iwqL, iqraw, iwkH, iwkL, ikraw);

    // 4. all elementwise post-processing in one launch
    fused_post<<<S_LEN, 256, 0, stream>>>(qbuf_bf, qeff_bf, kv, kv_a_norm_w, klat_bf,
                                          ikraw, idx_k_norm_w, idx_k_norm_b, ikH, ikL,
                                          iqraw, hid, idx_weights_w, cqH, cqL,
                                          cosT, sinT);

    // 5. qeff-nope (2048 blocks) + iscore causal (384 blocks) in one launch
    fused2<<<2048 + 384, blk, 0, stream>>>(qbuf_bf, wknt_bf, qeff_bf,
                                           cqH, cqL, ikH, ikL, iscore);

    // 6. topk (1536 blocks) overlapped with attention rows q<512 (512 blocks)
    topk_attnA<<<512 + 1536, blk, 0, stream>>>(iscore, topk, qeff_bf, klat_bf, o_lat_bf);

    // 7. attention rows q>=512 (needs topk)
    attn2b<<<S_LEN - TOPKN, blk, 0, stream>>>(qeff_bf, klat_bf, topk, o_lat_bf);

    // 8. V projection per head, then output projection
    gemm_s<__bf16><<<dim3(VDIM / GBN, S_LEN / GBM, NHEAD), blk, 0, stream>>>(
        o_lat_bf, wkv_b_bf + 128 * 512, attn_o_bf, 512,
        NHEAD * 512, 512, NHEAD * VDIM, 512, 256 * 512, VDIM);
    gemm_s<float><<<dim3(HIDDEN / GBN, S_LEN / GBM, 1), blk, 0, stream>>>(
        attn_o_bf, wo_bf, out, NHEAD * VDIM,
        NHEAD * VDIM, NHEAD * VDIM, HIDDEN, 0, 0, 0);
}

// Round 12
// 550.803 us; speedup vs baseline: 1.7788x; 1.7788x over previous
//
#include <hip/hip_runtime.h>
#include <hip/hip_bf16.h>
#include <stdint.h>
#include <math.h>

#define S_LEN 2048
#define HIDDEN 2048
#define NHEAD 16
#define QLORA 768
#define KVLORA 512
#define QKNOPE 128
#define QKROPE 64
#define QKHEAD 192
#define VDIM 128
#define HIN 8
#define DIN 128
#define TOPKN 512
#define EPSF 1e-5f
#define DLAT 576
#define SCALE_ATT 0.07216878364870322f  // 192^-0.5

typedef __bf16 bf16x8 __attribute__((ext_vector_type(8)));
typedef float  f32x4  __attribute__((ext_vector_type(4)));

static __device__ __forceinline__ float wave_reduce_sum(float v) {
    #pragma unroll
    for (int off = 32; off > 0; off >>= 1) v += __shfl_down(v, off);
    return v;
}

static __device__ __forceinline__ void splitw(__bf16* __restrict__ H,
                                              __bf16* __restrict__ L,
                                              size_t idx, float v) {
    __bf16 h = (__bf16)v;
    H[idx] = h;
    L[idx] = (__bf16)(v - (float)h);
}

// async global->LDS, 16B per lane; lds base must be wave-uniform (HW: base + lane*16)
// Used ONLY in GEMM streaming loops — in the register-heavy attention body it
// caused VGPR spills (R11: 140 VGPR, 110 MB scratch writes). Keep it out of attn.
static __device__ __forceinline__ void gll16(const __bf16* g, __bf16* lds_base) {
    __builtin_amdgcn_global_load_lds(
        (const __attribute__((address_space(1))) uint32_t*)g,
        (__attribute__((address_space(3))) uint32_t*)lds_base, 16, 0, 0);
}

// =============== fused prep: all casts / splits / transpose in ONE launch ===============
#define PREP_BLOCKS 17280
__global__ __launch_bounds__(256) void prep_all(
        const float* __restrict__ hid,     __bf16* hidH,  __bf16* hidL,
        const float* __restrict__ wq_a,    __bf16* wqaH,  __bf16* wqaL,
        const float* __restrict__ idx_wq_b,__bf16* iwqH,  __bf16* iwqL,
        const float* __restrict__ idx_wk,  __bf16* iwkH,  __bf16* iwkL,
        const float* __restrict__ wq_b,    __bf16* wq_b_bf,
        const float* __restrict__ wkv_a,   __bf16* wkv_a_bf,
        const float* __restrict__ wkv_b,   __bf16* wkv_b_bf,
        const float* __restrict__ wo,      __bf16* wo_bf,
        __bf16* wknt) {
    int b = blockIdx.x, tid = threadIdx.x;
    const float* src; __bf16 *dH = nullptr, *dL = nullptr, *dC = nullptr;
    int base;
    if (b < 4096)        { src = hid;      dH = hidH; dL = hidL; base = b; }
    else if (b < 5632)   { src = wq_a;     dH = wqaH; dL = wqaL; base = b - 4096; }
    else if (b < 6400)   { src = idx_wq_b; dH = iwqH; dL = iwqL; base = b - 5632; }
    else if (b < 6656)   { src = idx_wk;   dH = iwkH; dL = iwkL; base = b - 6400; }
    else if (b < 8960)   { src = wq_b;     dC = wq_b_bf;  base = b - 6656; }
    else if (b < 10112)  { src = wkv_a;    dC = wkv_a_bf; base = b - 8960; }
    else if (b < 12160)  { src = wkv_b;    dC = wkv_b_bf; base = b - 10112; }
    else if (b < 16256)  { src = wo;       dC = wo_bf;    base = b - 12160; }
    else {
        int e = ((b - 16256) * 256 + tid) * 4;
        int c = e & 511, d = (e >> 9) & 127, h = e >> 16;
        f32x4 v = *(const f32x4*)(wkv_b + ((size_t)(h * 256 + d)) * 512 + c);
        #pragma unroll
        for (int j = 0; j < 4; ++j)
            wknt[(size_t)h * 65536 + (c + j) * 128 + d] = (__bf16)v[j];
        return;
    }
    int i = (base * 256 + tid) * 4;
    f32x4 v = *(const f32x4*)(src + i);
    if (dC) {
        #pragma unroll
        for (int j = 0; j < 4; ++j) dC[i + j] = (__bf16)v[j];
    } else {
        #pragma unroll
        for (int j = 0; j < 4; ++j) splitw(dH, dL, i + j, v[j]);
    }
}

// ---------------- bf16 MFMA GEMM core: C = A*B^T (global_load_lds staging) ----------------
#define GBM 128
#define GBN 64
#define GBK 32
template <typename OutT>
static __device__ __forceinline__ void gemm_s_core(
        const __bf16* __restrict__ A, const __bf16* __restrict__ B,
        OutT* __restrict__ C, int K, int lda, int ldb, int ldc,
        int bx, int by) {
    __shared__ __bf16 sAs[GBM * GBK];
    __shared__ __bf16 sBs[GBN * GBK];
    int tid = threadIdx.x;
    int lane = tid & 63, wid = tid >> 6;
    int quad = lane >> 4, l16 = lane & 15;
    int wm = wid >> 1, wn = wid & 1;
    int row0 = by * GBM, col0 = bx * GBN;
    int lr = lane >> 2, lk = (lane & 3) * 8;   // lane -> (row-in-chunk, k-offset)

    f32x4 acc[4][2] = {};

    for (int k0 = 0; k0 < K; k0 += GBK) {
        #pragma unroll
        for (int c = 0; c < 2; ++c) {
            int rb = (wid * 2 + c) * 16;
            gll16(A + (size_t)(row0 + rb + lr) * lda + k0 + lk, sAs + rb * GBK);
        }
        gll16(B + (size_t)(col0 + wid * 16 + lr) * ldb + k0 + lk, sBs + wid * 16 * GBK);
        __syncthreads();
        bf16x8 af[4], bfr[2];
        #pragma unroll
        for (int mi = 0; mi < 4; ++mi)
            af[mi] = *(const bf16x8*)&sAs[(wm * 64 + mi * 16 + l16) * GBK + quad * 8];
        #pragma unroll
        for (int ni = 0; ni < 2; ++ni)
            bfr[ni] = *(const bf16x8*)&sBs[(wn * 32 + ni * 16 + l16) * GBK + quad * 8];
        #pragma unroll
        for (int mi = 0; mi < 4; ++mi)
            #pragma unroll
            for (int ni = 0; ni < 2; ++ni)
                acc[mi][ni] = __builtin_amdgcn_mfma_f32_16x16x32_bf16(
                    af[mi], bfr[ni], acc[mi][ni], 0, 0, 0);
        __syncthreads();
    }
    #pragma unroll
    for (int mi = 0; mi < 4; ++mi)
        #pragma unroll
        for (int ni = 0; ni < 2; ++ni)
            #pragma unroll
            for (int r = 0; r < 4; ++r) {
                int row = row0 + wm * 64 + mi * 16 + quad * 4 + r;
                int col = col0 + wn * 32 + ni * 16 + l16;
                C[(size_t)row * ldc + col] = (OutT)acc[mi][ni][r];
            }
}

template <typename OutT>
__global__ __launch_bounds__(256) void gemm_s(const __bf16* __restrict__ A,
                                              const __bf16* __restrict__ B,
                                              OutT* __restrict__ C,
                                              int K, int lda, int ldb, int ldc,
                                              long sA, long sB, long sC) {
    gemm_s_core<OutT>(A + (size_t)blockIdx.z * sA, B + (size_t)blockIdx.z * sB,
                      C + (size_t)blockIdx.z * sC, K, lda, ldb, ldc,
                      blockIdx.x, blockIdx.y);
}

// ------------- split-bf16 (~f32) MFMA GEMM core: C = Ah*Bh + Ah*Bl + Al*Bh -------------
template <bool CAUSAL>
static __device__ __forceinline__ void gemm3_core(
        const __bf16* __restrict__ Ah, const __bf16* __restrict__ Al,
        const __bf16* __restrict__ Bh, const __bf16* __restrict__ Bl,
        float* __restrict__ C, int K, int lda, int ldb, int ldc,
        int row_base, int bx, int by) {
    int row0 = by * GBM + row_base, col0 = bx * GBN;
    if (CAUSAL && col0 > row0 + GBM - 1) return;
    __shared__ __bf16 sAh[GBM * GBK], sAl[GBM * GBK];
    __shared__ __bf16 sBh[GBN * GBK], sBl[GBN * GBK];
    int tid = threadIdx.x;
    int lane = tid & 63, wid = tid >> 6;
    int quad = lane >> 4, l16 = lane & 15;
    int wm = wid >> 1, wn = wid & 1;
    int lr = lane >> 2, lk = (lane & 3) * 8;

    f32x4 acc[4][2] = {};

    for (int k0 = 0; k0 < K; k0 += GBK) {
        #pragma unroll
        for (int c = 0; c < 2; ++c) {
            int rb = (wid * 2 + c) * 16;
            size_t go = (size_t)(row0 + rb + lr) * lda + k0 + lk;
            gll16(Ah + go, sAh + rb * GBK);
            gll16(Al + go, sAl + rb * GBK);
        }
        {
            size_t go = (size_t)(col0 + wid * 16 + lr) * ldb + k0 + lk;
            gll16(Bh + go, sBh + wid * 16 * GBK);
            gll16(Bl + go, sBl + wid * 16 * GBK);
        }
        __syncthreads();
        bf16x8 afh[4], afl[4], bfh[2], bfl[2];
        #pragma unroll
        for (int mi = 0; mi < 4; ++mi) {
            int o = (wm * 64 + mi * 16 + l16) * GBK + quad * 8;
            afh[mi] = *(const bf16x8*)&sAh[o];
            afl[mi] = *(const bf16x8*)&sAl[o];
        }
        #pragma unroll
        for (int ni = 0; ni < 2; ++ni) {
            int o = (wn * 32 + ni * 16 + l16) * GBK + quad * 8;
            bfh[ni] = *(const bf16x8*)&sBh[o];
            bfl[ni] = *(const bf16x8*)&sBl[o];
        }
        #pragma unroll
        for (int mi = 0; mi < 4; ++mi)
            #pragma unroll
            for (int ni = 0; ni < 2; ++ni) {
                acc[mi][ni] = __builtin_amdgcn_mfma_f32_16x16x32_bf16(
                    afl[mi], bfh[ni], acc[mi][ni], 0, 0, 0);
                acc[mi][ni] = __builtin_amdgcn_mfma_f32_16x16x32_bf16(
                    afh[mi], bfl[ni], acc[mi][ni], 0, 0, 0);
                acc[mi][ni] = __builtin_amdgcn_mfma_f32_16x16x32_bf16(
                    afh[mi], bfh[ni], acc[mi][ni], 0, 0, 0);
            }
        __syncthreads();
    }
    #pragma unroll
    for (int mi = 0; mi < 4; ++mi)
        #pragma unroll
        for (int ni = 0; ni < 2; ++ni)
            #pragma unroll
            for (int r = 0; r < 4; ++r) {
                int row = row0 + wm * 64 + mi * 16 + quad * 4 + r;
                int col = col0 + wn * 32 + ni * 16 + l16;
                C[(size_t)row * ldc + col] = acc[mi][ni][r];
            }
}

// q_lora GEMM with K-split x4 (underfilled otherwise: 192 blocks on 256 CUs)
__global__ __launch_bounds__(256) void gemm3_ks(const __bf16* __restrict__ Ah,
                                                const __bf16* __restrict__ Al,
                                                const __bf16* __restrict__ Bh,
                                                const __bf16* __restrict__ Bl,
                                                float* __restrict__ Cpart,
                                                int Ksub, int lda, int ldb, int ldc,
                                                long sC) {
    int bz = blockIdx.z, koff = bz * Ksub;
    gemm3_core<false>(Ah + koff, Al + koff, Bh + koff, Bl + koff,
                      Cpart + (size_t)bz * sC, Ksub, lda, ldb, ldc, 0,
                      blockIdx.x, blockIdx.y);
}

// ============ fused mid GEMMs: qbuf | kv | iqraw | ikraw (independent) ============
__global__ __launch_bounds__(256) void fused_mid(
        const __bf16* __restrict__ qlH, const __bf16* __restrict__ qlL,
        const __bf16* __restrict__ wq_b_bf, __bf16* __restrict__ qbuf_bf,
        const __bf16* __restrict__ hidH, const __bf16* __restrict__ hidL,
        const __bf16* __restrict__ wkv_a_bf, float* __restrict__ kv,
        const __bf16* __restrict__ iwqH, const __bf16* __restrict__ iwqL,
        float* __restrict__ iqraw,
        const __bf16* __restrict__ iwkH, const __bf16* __restrict__ iwkL,
        float* __restrict__ ikraw) {
    int b = blockIdx.x;
    if (b < 768) {            // qbuf: [2048 x 3072] = ql * wq_b^T, K=768
        gemm_s_core<__bf16>(qlH, wq_b_bf, qbuf_bf, QLORA, QLORA, QLORA,
                            NHEAD * QKHEAD, b % 48, b / 48);
    } else if (b < 912) {     // kv: [2048 x 576] = hid * wkv_a^T, K=2048
        int r = b - 768;
        gemm_s_core<float>(hidH, wkv_a_bf, kv, HIDDEN, HIDDEN, HIDDEN, DLAT,
                           r % 9, r / 9);
    } else if (b < 1168) {    // iqraw: [2048 x 1024] = ql * idx_wq_b^T, K=768 (~f32)
        int r = b - 912;
        gemm3_core<false>(qlH, qlL, iwqH, iwqL, iqraw, QLORA, QLORA, QLORA,
                          HIN * DIN, 0, r & 15, r >> 4);
    } else {                  // ikraw: [2048 x 128] = hid * idx_wk^T, K=2048 (~f32)
        int r = b - 1168;
        gemm3_core<false>(hidH, hidL, iwkH, iwkL, ikraw, HIDDEN, HIDDEN, HIDDEN,
                          DIN, 0, r & 1, r >> 1);
    }
}

// ============ fused stage-2 GEMMs: qeff-nope (batched) | iscore (causal) ============
// iscore region: r in [0,384) ONLY (32 cols x 12 row-blocks, rows 512..2047).
__global__ __launch_bounds__(256) void fused2(
        const __bf16* __restrict__ qbuf_bf, const __bf16* __restrict__ wknt,
        __bf16* __restrict__ qeff,
        const __bf16* __restrict__ cqH, const __bf16* __restrict__ cqL,
        const __bf16* __restrict__ ikH, const __bf16* __restrict__ ikL,
        float* __restrict__ iscore) {
    int b = blockIdx.x;
    if (b < 2048) {           // qeff[...,0:512] per head: q_nope * wknt^T, K=128
        int bx = b & 7, by = (b >> 3) & 15, bz = b >> 7;
        gemm_s_core<__bf16>(qbuf_bf + bz * QKHEAD, wknt + (size_t)bz * 512 * 128,
                            qeff + bz * DLAT, 128, NHEAD * QKHEAD, 128,
                            NHEAD * DLAT, bx, by);
    } else {                  // iscore rows 512..2047, lower-triangle blocks, K=128
        int r = b - 2048;     // r in [0, 384)
        gemm3_core<true>(cqH, cqL, ikH, ikL, iscore, DIN, DIN, DIN, S_LEN,
                         TOPKN, r & 31, r >> 5);
    }
}

// ---------------- RMSNorm of 4 K-split partial sums -> split hi/lo bf16 ----------------
__global__ __launch_bounds__(256) void rmsnorm_split4(const float* __restrict__ p,
                                                      long ps,
                                                      const float* __restrict__ w,
                                                      __bf16* __restrict__ yH,
                                                      __bf16* __restrict__ yL, int ncols) {
    int row = blockIdx.x, tid = threadIdx.x;
    const float* p0 = p + (size_t)row * ncols;
    float ss = 0.f;
    for (int c = tid; c < ncols; c += 256) {
        float v = p0[c] + p0[ps + c] + p0[2 * ps + c] + p0[3 * ps + c];
        ss += v * v;
    }
    __shared__ float red[4];
    ss = wave_reduce_sum(ss);
    if ((tid & 63) == 0) red[tid >> 6] = ss;
    __syncthreads();
    float tot = red[0] + red[1] + red[2] + red[3];
    float inv = rsqrtf(tot / (float)ncols + EPSF);
    for (int c = tid; c < ncols; c += 256) {
        float v = p0[c] + p0[ps + c] + p0[2 * ps + c] + p0[3 * ps + c];
        splitw(yH, yL, (size_t)row * ncols + c, v * inv * w[c]);
    }
}

// ===== fused post: rope_qeff | kv_post | ik_post | cq2 — one block per position s =====
__global__ __launch_bounds__(256) void fused_post(
        const __bf16* __restrict__ qbuf, __bf16* __restrict__ qeff,
        const float* __restrict__ kv, const float* __restrict__ kvw,
        __bf16* __restrict__ klat,
        const float* __restrict__ ikraw, const float* __restrict__ lnw,
        const float* __restrict__ lnb, __bf16* __restrict__ ikH, __bf16* __restrict__ ikL,
        const float* __restrict__ iqraw, const float* __restrict__ hid,
        const float* __restrict__ iww, __bf16* __restrict__ cqH, __bf16* __restrict__ cqL,
        const float* __restrict__ cosT, const float* __restrict__ sinT) {
    int s = blockIdx.x, tid = threadIdx.x;
    int lane = tid & 63, wid = tid >> 6;

    // ---- A: rope on q -> qeff[...,512:576] ----
    for (int i = tid; i < NHEAD * 32; i += 256) {
        int h = i >> 5, d = i & 31;
        const __bf16* base = qbuf + (size_t)s * (NHEAD * QKHEAD) + h * QKHEAD + QKNOPE;
        float x1 = (float)base[d], x2 = (float)base[d + 32];
        float c1 = cosT[s * 64 + d],      s1 = sinT[s * 64 + d];
        float c2 = cosT[s * 64 + d + 32], s2 = sinT[s * 64 + d + 32];
        __bf16* o = qeff + (size_t)s * (NHEAD * DLAT) + h * DLAT + 512;
        o[d]      = (__bf16)(x1 * c1 - x2 * s1);
        o[d + 32] = (__bf16)(x2 * c2 + x1 * s2);
    }

    // ---- B: kv rmsnorm 512 + rope 64 -> klat ----
    {
        const float* row = kv + (size_t)s * DLAT;
        float ss = 0.f;
        for (int c = tid; c < KVLORA; c += 256) { float v = row[c]; ss += v * v; }
        __shared__ float redB[4];
        ss = wave_reduce_sum(ss);
        if (lane == 0) redB[wid] = ss;
        __syncthreads();
        float tot = redB[0] + redB[1] + redB[2] + redB[3];
        float inv = rsqrtf(tot / (float)KVLORA + EPSF);
        __bf16* orow = klat + (size_t)s * DLAT;
        for (int c = tid; c < KVLORA; c += 256)
            orow[c] = (__bf16)(row[c] * inv * kvw[c]);
        if (tid < 32) {
            int d = tid;
            float x1 = row[KVLORA + d], x2 = row[KVLORA + d + 32];
            float c1 = cosT[s * 64 + d],      s1 = sinT[s * 64 + d];
            float c2 = cosT[s * 64 + d + 32], s2 = sinT[s * 64 + d + 32];
            orow[512 + d]      = (__bf16)(x1 * c1 - x2 * s1);
            orow[512 + d + 32] = (__bf16)(x2 * c2 + x1 * s2);
        }
    }

    // ---- C: ik layer_norm(128) + rope -> split ----
    {
        float x = (tid < DIN) ? ikraw[(size_t)s * DIN + tid] : 0.f;
        __shared__ float redC1[4], redC2[4], sy[DIN];
        float sm = wave_reduce_sum(x);
        if (lane == 0) redC1[wid] = sm;
        __syncthreads();
        float mean = (redC1[0] + redC1[1] + redC1[2] + redC1[3]) / (float)DIN;
        float dx = (tid < DIN) ? (x - mean) : 0.f;
        float vs = wave_reduce_sum(dx * dx);
        if (lane == 0) redC2[wid] = vs;
        __syncthreads();
        float var = (redC2[0] + redC2[1] + redC2[2] + redC2[3]) / (float)DIN;
        if (tid < DIN) sy[tid] = dx * rsqrtf(var + EPSF) * lnw[tid] + lnb[tid];
        __syncthreads();
        size_t ro = (size_t)s * DIN;
        if (tid < 32) {
            int d = tid;
            float c1 = cosT[s * 64 + d],      s1 = sinT[s * 64 + d];
            float c2 = cosT[s * 64 + d + 32], s2 = sinT[s * 64 + d + 32];
            splitw(ikH, ikL, ro + d,      sy[d] * c1 - sy[d + 32] * s1);
            splitw(ikH, ikL, ro + d + 32, sy[d + 32] * c2 + sy[d] * s2);
        } else if (tid >= 64 && tid < DIN) {
            splitw(ikH, ikL, ro + tid, sy[tid]);
        }
        __syncthreads();
    }

    // ---- D: iw dots + fold into roped iq -> cq split ----
    {
        __shared__ float redD[4][HIN], siw[HIN];
        float a8[HIN] = {};
        const float* xr = hid + (size_t)s * HIDDEN;
        for (int c = tid; c < HIDDEN; c += 256) {
            float x = xr[c];
            #pragma unroll
            for (int h = 0; h < HIN; ++h) a8[h] += x * iww[h * HIDDEN + c];
        }
        #pragma unroll
        for (int h = 0; h < HIN; ++h) a8[h] = wave_reduce_sum(a8[h]);
        if (lane == 0)
            #pragma unroll
            for (int h = 0; h < HIN; ++h) redD[wid][h] = a8[h];
        __syncthreads();
        if (tid < HIN)
            siw[tid] = redD[0][tid] + redD[1][tid] + redD[2][tid] + redD[3][tid];
        __syncthreads();
        if (tid < DIN) {
            int d = tid;
            float acc = 0.f;
            float c1 = 0.f, s1 = 0.f;
            if (d < 64) { c1 = cosT[s * 64 + d]; s1 = sinT[s * 64 + d]; }
            #pragma unroll
            for (int h = 0; h < HIN; ++h) {
                const float* base = iqraw + ((size_t)s * HIN + h) * DIN;
                float v;
                if (d < 32)       v = base[d] * c1 - base[d + 32] * s1;
                else if (d < 64)  v = base[d] * c1 + base[d - 32] * s1;
                else              v = base[d];
                acc += siw[h] * v;
            }
            splitw(cqH, cqL, (size_t)s * DIN + d, acc * 0.03125f);
        }
    }
}

// ================= shared-memory structs for the merged topk/attention =================
#define SKS 584   // shorts per sK row (1168 B)
struct AttnSmem {
    short sK[32 * SKS];            // 37376 B
    float s_part[2][16][37];       // 4736
    float s_S[16][38];             // 2432
    float s_m[16], s_l[16], s_alpha[16], s_inv[16];   // 256  -> 44800 total
};
struct TopkSmem {
    uint32_t skey[S_LEN];          // 8192
    int hist[256];                 // 1024
    int wtot[4];
    uint32_t sp;
    int sr;
    int pos;
};

// inclusive suffix sum over 256 threads (1 barrier, shfl-based)
static __device__ __forceinline__ int suffix_scan256(int v, int tid, int* wtot) {
    int lane = tid & 63, w = tid >> 6;
    #pragma unroll
    for (int off = 1; off < 64; off <<= 1) {
        int u = __shfl_down(v, off);
        v += (lane + off < 64) ? u : 0;
    }
    int wt = __shfl(v, 0);
    if (lane == 0) wtot[w] = wt;
    __syncthreads();
    int add = 0;
    #pragma unroll
    for (int w2 = 0; w2 < 4; ++w2) add += (w2 > w) ? wtot[w2] : 0;
    return v + add;
}

// exclusive prefix sum over 256 threads (1 barrier, shfl-based)
static __device__ __forceinline__ int prefix_scan256_excl(int v, int tid, int* wtot) {
    int lane = tid & 63, w = tid >> 6;
    int orig = v;
    #pragma unroll
    for (int off = 1; off < 64; off <<= 1) {
        int u = __shfl_up(v, off);
        v += (lane >= off) ? u : 0;
    }
    int wt = __shfl(v, 63);
    if (lane == 0) wtot[w] = wt;
    __syncthreads();
    int add = 0;
    #pragma unroll
    for (int w2 = 0; w2 < 4; ++w2) add += (w2 < w) ? wtot[w2] : 0;
    return v + add - orig;
}

// ---- exact top-512 for one row q >= 512 (radix select, shfl scans) ----
static __device__ void topk_body(TopkSmem& sm, int qi,
                                 const float* __restrict__ iscore,
                                 int* __restrict__ topk) {
    int q = TOPKN + qi;
    int n = q + 1;
    int tid = threadIdx.x;
    const float* row = iscore + (size_t)q * S_LEN;
    for (int i = tid; i < n; i += 256) {
        uint32_t u = __float_as_uint(row[i]);
        sm.skey[i] = (u & 0x80000000u) ? ~u : (u | 0x80000000u);
    }
    uint32_t prefix = 0;
    int remk = TOPKN;
    for (int pass = 0; pass < 4; ++pass) {
        int shift = 24 - 8 * pass;
        uint32_t pmask = pass ? (0xFFFFFFFFu << (shift + 8)) : 0u;
        sm.hist[tid] = 0;
        __syncthreads();                  // covers skey staging (pass 0) + hist zero
        for (int i = tid; i < n; i += 256) {
            uint32_t u = sm.skey[i];
            if ((u & pmask) == prefix) atomicAdd(&sm.hist[(u >> shift) & 255], 1);
        }
        __syncthreads();
        int cnt = sm.hist[tid];
        int Sb = suffix_scan256(cnt, tid, sm.wtot);
        int Snext = Sb - cnt;
        if (Sb >= remk && Snext < remk) {
            sm.sp = prefix | ((uint32_t)tid << shift);
            sm.sr = remk - Snext;
        }
        __syncthreads();
        prefix = sm.sp;
        remk = sm.sr;
    }
    if (tid == 0) sm.pos = 0;
    __syncthreads();
    int* orow = topk + (size_t)q * TOPKN;
    for (int i = tid; i < n; i += 256) {
        if (sm.skey[i] > prefix) { int p = atomicAdd(&sm.pos, 1); orow[p] = i; }
    }
    __syncthreads();
    int base = sm.pos;   // == TOPKN - remk
    int chunk = (n + 255) >> 8;
    int lo = tid * chunk, hiEnd = lo + chunk;
    if (hiEnd > n) hiEnd = n;
    int cnt = 0;
    for (int i = lo; i < hiEnd; ++i) cnt += (sm.skey[i] == prefix);
    int r = prefix_scan256_excl(cnt, tid, sm.wtot);
    for (int i = lo; i < hiEnd && r < remk; ++i) {
        if (sm.skey[i] == prefix) { orow[base + r] = i; ++r; }
    }
}

// ---- absorbed-MLA flash attention body for one q (R10's proven structure) ----
static __device__ __forceinline__ void attn_body(AttnSmem& sm, int q,
                                 const __bf16* __restrict__ qeff,
                                 const __bf16* __restrict__ klat,
                                 const int* __restrict__ topk,
                                 __bf16* __restrict__ o_lat) {
    int tid = threadIdx.x;
    int lane = tid & 63, wid = tid >> 6;
    int l16 = lane & 15, quad = lane >> 4;
    int wn = wid & 1, wk = wid >> 1;

    int L = (q < TOPKN) ? (q + 1) : TOPKN;
    int nt = (L + 31) >> 5;
    const int* idxr = topk + (size_t)q * TOPKN;   // only deref'd when q >= TOPKN

    bf16x8 qf[9];
    const __bf16* qrow = qeff + (size_t)q * (NHEAD * DLAT) + l16 * DLAT + wk * 288 + quad * 8;
    #pragma unroll
    for (int s = 0; s < 9; ++s) qf[s] = *(const bf16x8*)(qrow + s * 32);

    if (tid < 16) { sm.s_m[tid] = -1e30f; sm.s_l[tid] = 0.f; }

    f32x4 oacc[8];
    #pragma unroll
    for (int i = 0; i < 8; ++i) oacc[i] = (f32x4){0.f, 0.f, 0.f, 0.f};

    int srow = tid >> 3, schk = tid & 7;

    for (int t = 0; t < nt; ++t) {
        int ki = t * 32 + srow;
        int gk = 0;
        if (ki < L) gk = (q < TOPKN) ? ki : idxr[ki];
        const uint4* src = (const uint4*)(klat + (size_t)gk * DLAT) + schk * 9;
        uint4* dst = (uint4*)((char*)sm.sK + srow * (SKS * 2) + schk * 144);
        #pragma unroll
        for (int c = 0; c < 9; ++c) dst[c] = src[c];
        __syncthreads();

        f32x4 sacc = {0.f, 0.f, 0.f, 0.f};
        const short* kbase = sm.sK + (wn * 16 + l16) * SKS + wk * 288 + quad * 8;
        #pragma unroll
        for (int s = 0; s < 9; ++s) {
            bf16x8 kf = *(const bf16x8*)(kbase + s * 32);
            sacc = __builtin_amdgcn_mfma_f32_16x16x32_bf16(qf[s], kf, sacc, 0, 0, 0);
        }
        #pragma unroll
        for (int r = 0; r < 4; ++r)
            sm.s_part[wk][quad * 4 + r][wn * 16 + l16] = sacc[r];
        __syncthreads();

        {
            int h = tid >> 4, k0 = (tid & 15) * 2;
            float v0 = -1e30f, v1 = -1e30f;
            if (t * 32 + k0 < L)
                v0 = (sm.s_part[0][h][k0] + sm.s_part[1][h][k0]) * SCALE_ATT;
            if (t * 32 + k0 + 1 < L)
                v1 = (sm.s_part[0][h][k0 + 1] + sm.s_part[1][h][k0 + 1]) * SCALE_ATT;
            float mt = fmaxf(v0, v1);
            #pragma unroll
            for (int o = 1; o < 16; o <<= 1) mt = fmaxf(mt, __shfl_xor(mt, o));
            float mold = sm.s_m[h];
            float mnew = fmaxf(mold, mt);
            float p0 = __expf(v0 - mnew), p1 = __expf(v1 - mnew);
            float ls = p0 + p1;
            #pragma unroll
            for (int o = 1; o < 16; o <<= 1) ls += __shfl_xor(ls, o);
            *(float2*)&sm.s_S[h][k0] = make_float2(p0, p1);
            if ((tid & 15) == 0) {
                float alpha = __expf(mold - mnew);
                sm.s_alpha[h] = alpha;
                sm.s_m[h] = mnew;
                sm.s_l[h] = sm.s_l[h] * alpha + ls;
            }
        }
        __syncthreads();

        f32x4 al4 = *(const f32x4*)&sm.s_alpha[quad * 4];
        // P A-frag, k-slot permutation j -> j^quad, loaded as 4 aligned b64s
        bf16x8 pf;
        int qhi = quad & 2, qlo = quad & 1;
        #pragma unroll
        for (int p = 0; p < 4; ++p) {
            float2 v = *(const float2*)&sm.s_S[l16][quad * 8 + ((2 * p) ^ qhi)];
            float e0 = qlo ? v.y : v.x, e1 = qlo ? v.x : v.y;
            pf[2 * p]     = (__bf16)e0;
            pf[2 * p + 1] = (__bf16)e1;
        }
        const __bf16* sKb = (const __bf16*)sm.sK;
        #pragma unroll
        for (int n = 0; n < 8; ++n) {
            int dim = wid * 128 + n * 16 + l16;
            bf16x8 vf;
            #pragma unroll
            for (int j = 0; j < 8; ++j)
                vf[j] = sKb[(quad * 8 + (j ^ quad)) * SKS + dim];
            #pragma unroll
            for (int r = 0; r < 4; ++r) oacc[n][r] *= al4[r];
            oacc[n] = __builtin_amdgcn_mfma_f32_16x16x32_bf16(pf, vf, oacc[n], 0, 0, 0);
        }
        __syncthreads();
    }

    if (tid < 16) sm.s_inv[tid] = 1.f / sm.s_l[tid];
    __syncthreads();
    f32x4 inv4 = *(const f32x4*)&sm.s_inv[quad * 4];
    #pragma unroll
    for (int n = 0; n < 8; ++n) {
        int dim = wid * 128 + n * 16 + l16;
        #pragma unroll
        for (int r = 0; r < 4; ++r) {
            int h = quad * 4 + r;
            o_lat[(size_t)q * 8192 + h * 512 + dim] = (__bf16)(oacc[n][r] * inv4[r]);
        }
    }
}

// ===== merged launch: blocks 0..511 attention rows q<512 (no topk dep) | 512..2047 topk =====
__global__ __launch_bounds__(256) void topk_attnA(
        const float* __restrict__ iscore, int* __restrict__ topk,
        const __bf16* __restrict__ qeff, const __bf16* __restrict__ klat,
        __bf16* __restrict__ o_lat) {
    __shared__ __align__(16) char pool[sizeof(AttnSmem)];
    int b = blockIdx.x;
    if (b < 512) {
        attn_body(*(AttnSmem*)pool, (b * 997) & 511, qeff, klat, nullptr, o_lat);
    } else {
        topk_body(*(TopkSmem*)pool, b - 512, iscore, topk);
    }
}

// ===== attention rows q >= 512 (needs topk) =====
__global__ __launch_bounds__(256) void attn2b(const __bf16* __restrict__ qeff,
                                              const __bf16* __restrict__ klat,
                                              const int* __restrict__ topk,
                                              __bf16* __restrict__ o_lat) {
    __shared__ __align__(16) char pool[sizeof(AttnSmem)];
    int q = TOPKN + (blockIdx.x * 997) % (S_LEN - TOPKN);
    attn_body(*(AttnSmem*)pool, q, qeff, klat, topk, o_lat);
}

extern "C" void kernel_launch(void* const* d_in, const int* in_sizes, int n_in,
                              void* d_out, int out_size, void* d_ws, size_t ws_size,
                              hipStream_t stream) {
    const float* hid          = (const float*)d_in[0];
    const float* cosT         = (const float*)d_in[1];
    const float* sinT         = (const float*)d_in[2];
    const float* wq_a         = (const float*)d_in[3];
    const float* q_a_norm_w   = (const float*)d_in[4];
    const float* wq_b         = (const float*)d_in[5];
    const float* wkv_a        = (const float*)d_in[6];
    const float* kv_a_norm_w  = (const float*)d_in[7];
    const float* wkv_b        = (const float*)d_in[8];
    const float* wo           = (const float*)d_in[9];
    const float* idx_wq_b     = (const float*)d_in[10];
    const float* idx_wk       = (const float*)d_in[11];
    const float* idx_k_norm_w = (const float*)d_in[12];
    const float* idx_k_norm_b = (const float*)d_in[13];
    const float* idx_weights_w= (const float*)d_in[14];
    float* out = (float*)d_out;

    char* ws = (char*)d_ws;
    size_t off = 0;
    auto alloc = [&](size_t nbytes) {
        void* p = (void*)(ws + off);
        off += (nbytes + 255) & ~(size_t)255;
        return p;
    };
    __bf16* qbuf_bf  = (__bf16*)alloc((size_t)S_LEN * NHEAD * QKHEAD * 2);
    float*  kv       = (float*) alloc((size_t)S_LEN * DLAT * 4);
    __bf16* klat_bf  = (__bf16*)alloc((size_t)S_LEN * DLAT * 2);
    __bf16* qeff_bf  = (__bf16*)alloc((size_t)S_LEN * NHEAD * DLAT * 2);
    int*    topk     = (int*)   alloc((size_t)S_LEN * TOPKN * 4);
    // union B: [hidH | wkv_a_bf] (early) / attn_o_bf (late)
    char* uB = (char*)alloc((size_t)S_LEN * HIDDEN * 2 + (size_t)DLAT * HIDDEN * 2);
    __bf16* hidH      = (__bf16*)uB;
    __bf16* wkv_a_bf  = (__bf16*)(uB + (size_t)S_LEN * HIDDEN * 2);
    __bf16* attn_o_bf = (__bf16*)uB;
    __bf16* hidL      = (__bf16*)alloc((size_t)S_LEN * HIDDEN * 2);
    // union C: qpart (earliest, 25.2MB) / indexer block (early) / o_lat (late, 33.6MB)
    char* uC = (char*)alloc((size_t)S_LEN * NHEAD * 512 * 2);
    float*  qpart    = (float*)uC;               // 4 x [2048 x 768] K-split partials
    __bf16* o_lat_bf = (__bf16*)uC;
    float* iqraw  = (float*)uC;
    float* ikraw  = (float*)(uC + 8388608);
    float* iscore = (float*)(uC + 11599872);
    __bf16* wq_b_bf  = (__bf16*)alloc((size_t)(NHEAD * QKHEAD) * QLORA * 2);
    __bf16* wkv_b_bf = (__bf16*)alloc((size_t)(NHEAD * 256) * KVLORA * 2);
    __bf16* wknt_bf  = (__bf16*)alloc((size_t)NHEAD * 512 * 128 * 2);
    __bf16* wo_bf    = (__bf16*)alloc((size_t)HIDDEN * (NHEAD * VDIM) * 2);
    __bf16* wqaH = (__bf16*)alloc((size_t)QLORA * HIDDEN * 2);
    __bf16* wqaL = (__bf16*)alloc((size_t)QLORA * HIDDEN * 2);
    __bf16* qlH  = (__bf16*)alloc((size_t)S_LEN * QLORA * 2);
    __bf16* qlL  = (__bf16*)alloc((size_t)S_LEN * QLORA * 2);
    __bf16* iwqH = (__bf16*)alloc((size_t)(HIN * DIN) * QLORA * 2);
    __bf16* iwqL = (__bf16*)alloc((size_t)(HIN * DIN) * QLORA * 2);
    __bf16* iwkH = (__bf16*)alloc((size_t)DIN * HIDDEN * 2);
    __bf16* iwkL = (__bf16*)alloc((size_t)DIN * HIDDEN * 2);
    __bf16* ikH  = (__bf16*)alloc((size_t)S_LEN * DIN * 2);
    __bf16* ikL  = (__bf16*)alloc((size_t)S_LEN * DIN * 2);
    __bf16* cqH  = (__bf16*)alloc((size_t)S_LEN * DIN * 2);
    __bf16* cqL  = (__bf16*)alloc((size_t)S_LEN * DIN * 2);
    (void)ws_size; (void)in_sizes; (void)n_in; (void)out_size;

    dim3 blk(256);

    // 1. all casts / splits / transpose in one launch
    prep_all<<<PREP_BLOCKS, blk, 0, stream>>>(
        hid, hidH, hidL, wq_a, wqaH, wqaL, idx_wq_b, iwqH, iwqL,
        idx_wk, iwkH, iwkL, wq_b, wq_b_bf, wkv_a, wkv_a_bf,
        wkv_b, wkv_b_bf, wo, wo_bf, wknt_bf);

    // 2. q_lora (~f32, K-split x4 for occupancy) + rmsnorm(sum of partials)
    gemm3_ks<<<dim3(QLORA / GBN, S_LEN / GBM, 4), blk, 0, stream>>>(
        hidH, hidL, wqaH, wqaL, qpart, HIDDEN / 4, HIDDEN, HIDDEN, QLORA,
        (long)S_LEN * QLORA);
    rmsnorm_split4<<<S_LEN, 256, 0, stream>>>(qpart, (long)S_LEN * QLORA,
                                              q_a_norm_w, qlH, qlL, QLORA);

    // 3. four independent GEMMs in one launch: qbuf | kv | iqraw | ikraw
    fused_mid<<<1200, blk, 0, stream>>>(qlH, qlL, wq_b_bf, qbuf_bf,
                                        hidH, hidL, wkv_a_bf, kv,
                                        iwqH, iwqL, iqraw, iwkH, iwkL, ikraw);

    // 4. all elementwise post-processing in one launch
    fused_post<<<S_LEN, 256, 0, stream>>>(qbuf_bf, qeff_bf, kv, kv_a_norm_w, klat_bf,
                                          ikraw, idx_k_norm_w, idx_k_norm_b, ikH, ikL,
                                          iqraw, hid, idx_weights_w, cqH, cqL,
                                          cosT, sinT);

    // 5. qeff-nope (2048 blocks) + iscore causal (384 blocks) in one launch
    fused2<<<2048 + 384, blk, 0, stream>>>(qbuf_bf, wknt_bf, qeff_bf,
                                           cqH, cqL, ikH, ikL, iscore);

    // 6. topk (1536 blocks) overlapped with attention rows q<512 (512 blocks)
    topk_attnA<<<512 + 1536, blk, 0, stream>>>(iscore, topk, qeff_bf, klat_bf, o_lat_bf);

    // 7. attention rows q>=512 (needs topk)
    attn2b<<<S_LEN - TOPKN, blk, 0, stream>>>(qeff_bf, klat_bf, topk, o_lat_bf);

    // 8. V projection per head, then output projection
    gemm_s<__bf16><<<dim3(VDIM / GBN, S_LEN / GBM, NHEAD), blk, 0, stream>>>(
        o_lat_bf, wkv_b_bf + 128 * 512, attn_o_bf, 512,
        NHEAD * 512, 512, NHEAD * VDIM, 512, 256 * 512, VDIM);
    gemm_s<float><<<dim3(HIDDEN / GBN, S_LEN / GBM, 1), blk, 0, stream>>>(
        attn_o_bf, wo_bf, out, NHEAD * VDIM,
        NHEAD * VDIM, NHEAD * VDIM, HIDDEN, 0, 0, 0);
}